// Round 12
// baseline (76.735 us; speedup 1.0000x reference)
//
#include <hip/hip_runtime.h>
#include <math.h>

#define N_PTR 2048
#define M_NU  4096
#define DIM   512
#define KCLS  1000

static constexpr float LAMBDA_ = 0.1f;
static constexpr float EPS_ = 1e-8f;
static constexpr float INV_DENOM = 1.0f / (0.1f * 0.5f + 1e-8f);   // 1/(lambda*eps+EPS)

typedef short short8 __attribute__((ext_vector_type(8)));
typedef unsigned short u16x8 __attribute__((ext_vector_type(8)));
typedef float f32x4 __attribute__((ext_vector_type(4)));

__device__ __forceinline__ unsigned short f2bf(float x) {
  unsigned u = __float_as_uint(x);
  u += 0x7fff + ((u >> 16) & 1);     // round-to-nearest-even
  return (unsigned short)(u >> 16);
}
__device__ __forceinline__ float bf2f(unsigned short h) {
  return __uint_as_float(((unsigned)h) << 16);
}

__device__ __forceinline__ void gload16(const void* g, void* l) {
  __builtin_amdgcn_global_load_lds(
      (const __attribute__((address_space(1))) unsigned int*)g,
      (__attribute__((address_space(3))) unsigned int*)l, 16, 0, 0);
}

// ---------- block reduction helpers (blockDim.x == 256) ----------
__device__ __forceinline__ float blk_reduce_sum(float v, float* red) {
  #pragma unroll
  for (int off = 32; off > 0; off >>= 1) v += __shfl_down(v, off);
  __syncthreads();
  if ((threadIdx.x & 63) == 0) red[threadIdx.x >> 6] = v;
  __syncthreads();
  return red[0] + red[1] + red[2] + red[3];
}

__device__ __forceinline__ float blk_reduce_max(float v, float* red) {
  #pragma unroll
  for (int off = 32; off > 0; off >>= 1) v = fmaxf(v, __shfl_down(v, off));
  __syncthreads();
  if ((threadIdx.x & 63) == 0) red[threadIdx.x >> 6] = v;
  __syncthreads();
  return fmaxf(fmaxf(red[0], red[1]), fmaxf(red[2], red[3]));
}

// ---------- 1. prep: normalize+cast An/Bn/Ae/Be (blocks 0..3071) + CE loss (3072..7167) ----------
// Ae[n] = normalize(cls_w[pl[n]]), Be[m] = normalize(cls_w[nl[m]]) — materialized,
// so the S-GEMM needs no gathers at all.
__global__ __launch_bounds__(256) void prep_kernel(
    const float* __restrict__ ptr_f, const float* __restrict__ nu_f,
    const float* __restrict__ cls_f, const float* __restrict__ logits,
    const int* __restrict__ pl, const int* __restrict__ nl,
    const int* __restrict__ labels,
    unsigned short* __restrict__ An, unsigned short* __restrict__ Bn,
    unsigned short* __restrict__ Ae, unsigned short* __restrict__ Be,
    float* __restrict__ losses) {
  __shared__ float red[4];
  int b = blockIdx.x;
  int tid = threadIdx.x;
  if (b < 3072) {                       // ---- normalize + bf16 cast, one wave per row
    int gid = b * 256 + tid;
    int row = gid >> 6, lane = gid & 63;
    const float* src; unsigned short* dst;
    if (row < N_PTR) {
      src = ptr_f + (size_t)row * DIM;           dst = An + (size_t)row * DIM;
    } else if (row < N_PTR + M_NU) {
      int r = row - N_PTR;
      src = nu_f + (size_t)r * DIM;              dst = Bn + (size_t)r * DIM;
    } else if (row < N_PTR + M_NU + N_PTR) {
      int r = row - N_PTR - M_NU;
      src = cls_f + (size_t)pl[r] * DIM;         dst = Ae + (size_t)r * DIM;
    } else {
      int r = row - N_PTR - M_NU - N_PTR;
      src = cls_f + (size_t)nl[r] * DIM;         dst = Be + (size_t)r * DIM;
    }
    const float4* rp = (const float4*)src;
    float4 a = rp[lane * 2], bq = rp[lane * 2 + 1];
    float v[8] = {a.x, a.y, a.z, a.w, bq.x, bq.y, bq.z, bq.w};
    float s = 0.f;
    #pragma unroll
    for (int j = 0; j < 8; ++j) s = fmaf(v[j], v[j], s);
    #pragma unroll
    for (int off = 32; off > 0; off >>= 1) s += __shfl_xor(s, off);
    float inv = 1.0f / fmaxf(sqrtf(s), EPS_);
    u16x8 ov;
    #pragma unroll
    for (int j = 0; j < 8; ++j) ov[j] = f2bf(v[j] * inv);
    *(u16x8*)(dst + lane * 8) = ov;
  } else {                              // ---- CE loss (one block per nu row, float4 reads)
    int row = b - 3072;
    const float* x = logits + (size_t)row * KCLS;
    const float4* x4 = (const float4*)x;          // 4000B rows are 16B-aligned
    float4 v = make_float4(0.f, 0.f, 0.f, 0.f);
    float mx_loc = -INFINITY;
    if (tid < 250) {                              // 250*4 = 1000
      v = x4[tid];
      mx_loc = fmaxf(fmaxf(v.x, v.y), fmaxf(v.z, v.w));
    }
    float mx = blk_reduce_max(mx_loc, red);
    float se_loc = 0.f;
    if (tid < 250)
      se_loc = __expf(v.x - mx) + __expf(v.y - mx) + __expf(v.z - mx) + __expf(v.w - mx);
    float se = blk_reduce_sum(se_loc, red);
    if (tid == 0) losses[row] = mx + logf(se) - x[labels[row]];
  }
}

// ---------- 2. colsums (blocks 0..95) + gmax (block 96) ----------
// csum_part: 0..15 An, 16..47 Bn, 48..63 Ae, 64..95 Be (f32 column partials).
__global__ __launch_bounds__(256) void colsum_kernel(
    const unsigned short* __restrict__ An, const unsigned short* __restrict__ Bn,
    const unsigned short* __restrict__ Ae, const unsigned short* __restrict__ Be,
    const float* __restrict__ nloss, float* __restrict__ csum_part,
    unsigned* __restrict__ gbits) {
  __shared__ float red[4];
  int b = blockIdx.x, tid = threadIdx.x;
  if (b == 96) {
    float mloc = 0.f;
    for (int i = tid; i < M_NU; i += 256) mloc = fmaxf(mloc, nloss[i]);
    float mx = blk_reduce_max(mloc, red);
    if (tid == 0) *gbits = __float_as_uint(mx);
    return;
  }
  const unsigned short* basep; int n0;
  if (b < 16)      { basep = An; n0 = b * 128; }
  else if (b < 48) { basep = Bn; n0 = (b - 16) * 128; }
  else if (b < 64) { basep = Ae; n0 = (b - 48) * 128; }
  else             { basep = Be; n0 = (b - 64) * 128; }
  float a0 = 0.f, a1 = 0.f;
  for (int i = 0; i < 128; ++i) {
    unsigned v = *(const unsigned*)(basep + (size_t)(n0 + i) * DIM + tid * 2);
    a0 += bf2f((unsigned short)(v & 0xffffu));
    a1 += bf2f((unsigned short)(v >> 16));
  }
  csum_part[(size_t)b * DIM + tid * 2]     = a0;
  csum_part[(size_t)b * DIM + tid * 2 + 1] = a1;
}

// ---------- 3. concat-K S-GEMM: acc = An.Bn^T + Ae.Be^T (two K=512 passes) ----------
// 128x128 tile, BK=64, 4 waves 2x2 (r10-validated structure); gather-free DRO epilogue.
__global__ __launch_bounds__(256) void sgemm_kernel(
    const unsigned short* __restrict__ An, const unsigned short* __restrict__ Bn,
    const unsigned short* __restrict__ Ae, const unsigned short* __restrict__ Be,
    unsigned short* __restrict__ Tb, const int* __restrict__ nl,
    const float* __restrict__ nu_loss, const unsigned* __restrict__ gbits,
    float* __restrict__ pr, float* __restrict__ pr2) {
  __shared__ unsigned short Alds[128 * 64];
  __shared__ unsigned short Blds[128 * 64];
  const int tid = threadIdx.x;
  const int w = tid >> 6, lane = tid & 63;
  const int brow = blockIdx.y * 128, bcol = blockIdx.x * 128;
  const int wr = w >> 1, wc = w & 1;

  const int sr = lane >> 3;            // row within 8-row staging group
  const int sc = lane & 7;             // 16B chunk within 128B row
  const int schunk = (sc ^ sr) * 8;    // pre-swizzled global element offset

  f32x4 acc[4][4] = {};

  #pragma unroll
  for (int half = 0; half < 2; ++half) {
    const unsigned short* Ab = half ? Ae : An;
    const unsigned short* Bb = half ? Be : Bn;
    for (int k0 = 0; k0 < DIM; k0 += 64) {
      #pragma unroll
      for (int i = 0; i < 4; ++i) {
        int j = w * 4 + i;              // staging slot, 8 rows each
        int r = j * 8 + sr;
        gload16(Ab + (size_t)(brow + r) * DIM + k0 + schunk, (char*)Alds + j * 1024);
        gload16(Bb + (size_t)(bcol + r) * DIM + k0 + schunk, (char*)Blds + j * 1024);
      }
      __syncthreads();
      #pragma unroll
      for (int kk = 0; kk < 2; ++kk) {
        const int koff = kk * 64 + (lane >> 4) * 16;
        short8 af[4], bfr[4];
        #pragma unroll
        for (int mi = 0; mi < 4; ++mi) {
          int r = wr * 64 + mi * 16 + (lane & 15);
          af[mi] = *(const short8*)((const char*)Alds + r * 128 + (koff ^ ((r & 7) << 4)));
        }
        #pragma unroll
        for (int ni = 0; ni < 4; ++ni) {
          int r = wc * 64 + ni * 16 + (lane & 15);
          bfr[ni] = *(const short8*)((const char*)Blds + r * 128 + (koff ^ ((r & 7) << 4)));
        }
        #pragma unroll
        for (int mi = 0; mi < 4; ++mi)
          #pragma unroll
          for (int ni = 0; ni < 4; ++ni)
            acc[mi][ni] = __builtin_amdgcn_mfma_f32_16x16x32_bf16(af[mi], bfr[ni], acc[mi][ni], 0, 0, 0);
      }
      __syncthreads();
    }
  }

  // gather-free epilogue: t = exp(fac*acc + a_r), acc = s + gy
  // C/D layout: col = lane&15, row = (lane>>4)*4 + reg  [verified]
  const float gmax = __uint_as_float(*gbits);
  const float fac = LAMBDA_ * INV_DENOM;            // ~2
  int cols[4]; float a_r[4]; float loss_r[4];
  #pragma unroll
  for (int ni = 0; ni < 4; ++ni) {
    cols[ni]   = bcol + wc * 64 + ni * 16 + (lane & 15);
    loss_r[ni] = nu_loss[cols[ni]];
    a_r[ni]    = (loss_r[ni] - gmax - 2.f * LAMBDA_) * INV_DENOM;
  }
  #pragma unroll
  for (int mi = 0; mi < 4; ++mi) {
    #pragma unroll
    for (int j = 0; j < 4; ++j) {
      int row = brow + wr * 64 + mi * 16 + (lane >> 4) * 4 + j;
      float rowacc = 0.f, rowacc2 = 0.f;
      #pragma unroll
      for (int ni = 0; ni < 4; ++ni) {
        float t = __expf(fmaf(fac, acc[mi][ni][j], a_r[ni]));
        unsigned short tb = f2bf(t);
        Tb[(size_t)row * M_NU + cols[ni]] = tb;
        float tt = bf2f(tb);
        rowacc  += tt;
        rowacc2 += tt * loss_r[ni];
      }
      #pragma unroll
      for (int off = 1; off < 16; off <<= 1) {
        rowacc  += __shfl_xor(rowacc, off);
        rowacc2 += __shfl_xor(rowacc2, off);
      }
      if ((lane & 15) == 0) {
        pr [(size_t)(blockIdx.x * 2 + wc) * N_PTR + row] = rowacc;
        pr2[(size_t)(blockIdx.x * 2 + wc) * N_PTR + row] = rowacc2;
      }
    }
  }
}

// ---------- 4. colpass (blocks 0..255) + T/D row reduce (blocks 256..271) ----------
__global__ __launch_bounds__(256) void colpass_td_kernel(
    const unsigned short* __restrict__ Tb, const float* __restrict__ pr,
    const float* __restrict__ pr2, float* __restrict__ partial,
    float* __restrict__ T_part, float* __restrict__ D_part) {
  __shared__ float sh[64];
  int b = blockIdx.x, tid = threadIdx.x;
  if (b < 256) {                       // ---- column partial: 512 m-cols x 64 n-rows
    int bx = b & 7, by = b >> 3;
    int m0 = bx * 512 + tid * 2;
    int n0 = by * 64;
    if (tid < 64) {
      float rs = 0.f;
      #pragma unroll 4
      for (int cb = 0; cb < 64; ++cb) rs += pr[(size_t)cb * N_PTR + n0 + tid];
      sh[tid] = 1.0f / (rs + EPS_);
    }
    __syncthreads();
    float a0 = 0.f, a1 = 0.f;
    #pragma unroll 4
    for (int i = 0; i < 64; ++i) {
      unsigned tv = *(const unsigned*)(Tb + (size_t)(n0 + i) * M_NU + m0);
      float wv = sh[i];
      a0 = fmaf(bf2f((unsigned short)(tv & 0xffffu)), wv, a0);
      a1 = fmaf(bf2f((unsigned short)(tv >> 16)), wv, a1);
    }
    *(float2*)(partial + (size_t)by * M_NU + m0) = make_float2(a0, a1);
  } else {                             // ---- T/D over 128 rows
    int n = (b - 256) * 128 + (tid & 127);
    float tl = 0.f, dl = 0.f;
    if (tid < 128) {
      float rs = 0.f, wl = 0.f;
      #pragma unroll 4
      for (int cb = 0; cb < 64; ++cb) {
        rs += pr [(size_t)cb * N_PTR + n];
        wl += pr2[(size_t)cb * N_PTR + n];
      }
      float wi = 1.0f / (rs + EPS_);
      tl = rs * wi; dl = wl * wi;
    }
    __syncthreads();                   // reuse sh as red scratch
    #pragma unroll
    for (int off = 32; off > 0; off >>= 1) { tl += __shfl_down(tl, off); dl += __shfl_down(dl, off); }
    if ((tid & 63) == 0) { sh[tid >> 6] = tl; sh[4 + (tid >> 6)] = dl; }
    __syncthreads();
    if (tid == 0) {
      T_part[b - 256] = sh[0] + sh[1] + sh[2] + sh[3];
      D_part[b - 256] = sh[4] + sh[5] + sh[6] + sh[7];
    }
  }
}

// ---------- 5. final: blocks 0..15 scaled probs; block 16 scalars + colsum-dot means ----------
__global__ __launch_bounds__(256) void final_kernel(const float* __restrict__ partial,
    const float* __restrict__ T_part, const float* __restrict__ D_part,
    const float* __restrict__ csum_part, float* __restrict__ out) {
  __shared__ float red[4];
  int b = blockIdx.x, tid = threadIdx.x;
  float T = 0.f;
  #pragma unroll
  for (int i = 0; i < 16; ++i) T += T_part[i];
  float scale = (1.0f / (float)N_PTR) / (T / (float)N_PTR + EPS_);
  if (b < 16) {
    int m = b * 256 + tid;
    float raw = 0.f;
    #pragma unroll
    for (int c = 0; c < 32; ++c) raw += partial[(size_t)c * M_NU + m];
    out[2 + m] = raw * scale;
  } else {
    float D = 0.f;
    #pragma unroll
    for (int i = 0; i < 16; ++i) D += D_part[i];
    float lx = 0.f, ly = 0.f;
    for (int c = tid; c < DIM; c += 256) {
      float sA = 0.f, sB = 0.f, sPe = 0.f, sQe = 0.f;
      #pragma unroll 4
      for (int p = 0; p < 16; ++p)  sA  += csum_part[(size_t)p * DIM + c];
      #pragma unroll 4
      for (int p = 16; p < 48; ++p) sB  += csum_part[(size_t)p * DIM + c];
      #pragma unroll 4
      for (int p = 48; p < 64; ++p) sPe += csum_part[(size_t)p * DIM + c];
      #pragma unroll 4
      for (int p = 64; p < 96; ++p) sQe += csum_part[(size_t)p * DIM + c];
      lx = fmaf(sA, sB, lx);
      ly = fmaf(sPe, sQe, ly);
    }
    float dX = blk_reduce_sum(lx, red);
    float dY = blk_reduce_sum(ly, red);
    if (tid == 0) {
      float dro = D * scale;
      const float invNM = 1.0f / ((float)N_PTR * (float)M_NU);
      float mcx = 1.f - dX * invNM;
      float mcy = 1.f - dY * invNM;
      out[0] = dro;
      out[1] = dro;
      out[2 + M_NU] = mcx + mcy;
      out[3 + M_NU] = mcx;
      out[4 + M_NU] = mcy;
    }
  }
}

extern "C" void kernel_launch(void* const* d_in, const int* in_sizes, int n_in,
                              void* d_out, int out_size, void* d_ws, size_t ws_size,
                              hipStream_t stream) {
  const float* ptr_feat = (const float*)d_in[0];
  const int*   ptr_lab  = (const int*)d_in[2];
  const float* nu_feat  = (const float*)d_in[3];
  const float* nu_log   = (const float*)d_in[4];
  const int*   nu_lab   = (const int*)d_in[5];
  const float* cls_w    = (const float*)d_in[6];
  float* out = (float*)d_out;

  char* base = (char*)d_ws;
  unsigned short* Tb = (unsigned short*)base;                          // 16 MB
  unsigned short* An = (unsigned short*)(base + 16u * 1024 * 1024);    // 2 MB
  unsigned short* Bn = (unsigned short*)(base + 18u * 1024 * 1024);    // 4 MB
  unsigned short* Ae = (unsigned short*)(base + 22u * 1024 * 1024);    // 2 MB
  unsigned short* Be = (unsigned short*)(base + 24u * 1024 * 1024);    // 4 MB
  float* fb          = (float*)(base + 28u * 1024 * 1024);
  float* nloss     = fb;                            // 4096
  unsigned* gbits  = (unsigned*)(nloss + 4096);     // 1 (+63 pad)
  float* pr        = nloss + 4096 + 64;             // 64 * 2048
  float* pr2       = pr  + 64 * N_PTR;              // 64 * 2048
  float* partial   = pr2 + 64 * N_PTR;              // 32 * 4096
  float* T_part    = partial + 32 * M_NU;           // 16
  float* D_part    = T_part + 16;                   // 16 (+pad)
  float* csum_part = D_part + 48;                   // 96 * 512

  prep_kernel<<<dim3(3072 + M_NU), 256, 0, stream>>>(
      ptr_feat, nu_feat, cls_w, nu_log, ptr_lab, nu_lab, nu_lab,
      An, Bn, Ae, Be, nloss);
  colsum_kernel<<<dim3(97), 256, 0, stream>>>(An, Bn, Ae, Be, nloss, csum_part, gbits);
  sgemm_kernel<<<dim3(M_NU / 128, N_PTR / 128), 256, 0, stream>>>(
      An, Bn, Ae, Be, Tb, nu_lab, nloss, gbits, pr, pr2);
  colpass_td_kernel<<<dim3(272), 256, 0, stream>>>(Tb, pr, pr2, partial, T_part, D_part);
  final_kernel<<<dim3(17), 256, 0, stream>>>(partial, T_part, D_part, csum_part, out);
}

// Round 13
// 76.538 us; speedup vs baseline: 1.0026x; 1.0026x over previous
//
#include <hip/hip_runtime.h>
#include <math.h>

#define N_PTR 2048
#define M_NU  4096
#define DIM   512
#define KCLS  1000
#define KPAD  1024

static constexpr float LAMBDA_ = 0.1f;
static constexpr float EPS_ = 1e-8f;
static constexpr float INV_DENOM = 1.0f / (0.1f * 0.5f + 1e-8f);   // 1/(lambda*eps+EPS)

typedef short short8 __attribute__((ext_vector_type(8)));
typedef unsigned short u16x8 __attribute__((ext_vector_type(8)));
typedef float f32x4 __attribute__((ext_vector_type(4)));

__device__ __forceinline__ unsigned short f2bf(float x) {
  unsigned u = __float_as_uint(x);
  u += 0x7fff + ((u >> 16) & 1);     // round-to-nearest-even
  return (unsigned short)(u >> 16);
}
__device__ __forceinline__ float bf2f(unsigned short h) {
  return __uint_as_float(((unsigned)h) << 16);
}

__device__ __forceinline__ void gload16(const void* g, void* l) {
  __builtin_amdgcn_global_load_lds(
      (const __attribute__((address_space(1))) unsigned int*)g,
      (__attribute__((address_space(3))) unsigned int*)l, 16, 0, 0);
}

// ---------- block reduction helpers (blockDim.x == 256) ----------
__device__ __forceinline__ float blk_reduce_sum(float v, float* red) {
  #pragma unroll
  for (int off = 32; off > 0; off >>= 1) v += __shfl_down(v, off);
  __syncthreads();
  if ((threadIdx.x & 63) == 0) red[threadIdx.x >> 6] = v;
  __syncthreads();
  return red[0] + red[1] + red[2] + red[3];
}

__device__ __forceinline__ float blk_reduce_max(float v, float* red) {
  #pragma unroll
  for (int off = 32; off > 0; off >>= 1) v = fmaxf(v, __shfl_down(v, off));
  __syncthreads();
  if ((threadIdx.x & 63) == 0) red[threadIdx.x >> 6] = v;
  __syncthreads();
  return fmaxf(fmaxf(red[0], red[1]), fmaxf(red[2], red[3]));
}

// ---------- 1. fused prep: normalize+cast (blocks 0..1791) + CE loss (blocks 1792..5887) ----------
__global__ __launch_bounds__(256) void prep_kernel(
    const float* __restrict__ ptr_f, const float* __restrict__ nu_f,
    const float* __restrict__ cls_f, const float* __restrict__ logits,
    const int* __restrict__ labels, unsigned short* __restrict__ An,
    unsigned short* __restrict__ Bn, unsigned short* __restrict__ Cn,
    float* __restrict__ losses) {
  __shared__ float red[4];
  int b = blockIdx.x;
  if (b < 1792) {                       // ---- normalize + bf16 cast
    int gid = b * 256 + threadIdx.x;
    int row = gid >> 6, lane = gid & 63;
    const float* src; unsigned short* dst; int lrow; int in_rows;
    if (row < N_PTR)             { src = ptr_f; dst = An; lrow = row;                in_rows = N_PTR; }
    else if (row < N_PTR + M_NU) { src = nu_f;  dst = Bn; lrow = row - N_PTR;        in_rows = M_NU; }
    else                         { src = cls_f; dst = Cn; lrow = row - N_PTR - M_NU; in_rows = KCLS; }
    u16x8 ov;
    if (lrow < in_rows) {
      const float4* rp = (const float4*)(src + (size_t)lrow * DIM);
      float4 a = rp[lane * 2], bq = rp[lane * 2 + 1];
      float v[8] = {a.x, a.y, a.z, a.w, bq.x, bq.y, bq.z, bq.w};
      float s = 0.f;
      #pragma unroll
      for (int j = 0; j < 8; ++j) s = fmaf(v[j], v[j], s);
      #pragma unroll
      for (int off = 32; off > 0; off >>= 1) s += __shfl_xor(s, off);
      float inv = 1.0f / fmaxf(sqrtf(s), EPS_);
      #pragma unroll
      for (int j = 0; j < 8; ++j) ov[j] = f2bf(v[j] * inv);
    } else {
      #pragma unroll
      for (int j = 0; j < 8; ++j) ov[j] = 0;
    }
    *(u16x8*)(dst + (size_t)lrow * DIM + lane * 8) = ov;
  } else {                              // ---- CE loss (one block per nu row, float4 reads)
    int row = b - 1792;
    int tid = threadIdx.x;
    const float* x = logits + (size_t)row * KCLS;
    const float4* x4 = (const float4*)x;          // 4000B rows are 16B-aligned
    float4 v = make_float4(0.f, 0.f, 0.f, 0.f);
    float mx_loc = -INFINITY;
    if (tid < 250) {                              // 250*4 = 1000
      v = x4[tid];
      mx_loc = fmaxf(fmaxf(v.x, v.y), fmaxf(v.z, v.w));
    }
    float mx = blk_reduce_max(mx_loc, red);
    float se_loc = 0.f;
    if (tid < 250)
      se_loc = __expf(v.x - mx) + __expf(v.y - mx) + __expf(v.z - mx) + __expf(v.w - mx);
    float se = blk_reduce_sum(se_loc, red);
    if (tid == 0) losses[row] = mx + logf(se) - x[labels[row]];
  }
}

// ---------- 2a. G-GEMM (4 waves, BM=64) — byte-identical to round 10 MODE 0 ----------
template <int BM, int MODE>
__global__ __launch_bounds__(256) void mfma_gemm(
    const unsigned short* __restrict__ A, const unsigned short* __restrict__ B,
    unsigned short* __restrict__ Gfb, unsigned short* __restrict__ Tb,
    const int* __restrict__ pl, const int* __restrict__ nl,
    const float* __restrict__ nu_loss, unsigned* __restrict__ gbits,
    float* __restrict__ pr, float* __restrict__ pr2,
    float* __restrict__ s_part, float* __restrict__ gy_part, int ldc) {
  constexpr int FR = BM / 32;          // frags per wave dim (128->4, 64->2)
  constexpr int WSPAN = BM / 2;
  __shared__ unsigned short Alds[BM * 64];
  __shared__ unsigned short Blds[BM * 64];
  __shared__ float red[4];
  const int tid = threadIdx.x;
  const int w = tid >> 6, lane = tid & 63;
  const int brow = blockIdx.y * BM, bcol = blockIdx.x * BM;
  const int wr = w >> 1, wc = w & 1;

  if (MODE == 0 && blockIdx.x == 0 && blockIdx.y == 0) {
    float mloc = 0.f;
    for (int i = tid; i < M_NU; i += 256) mloc = fmaxf(mloc, nu_loss[i]);
    float mx = blk_reduce_max(mloc, red);
    if (tid == 0) *gbits = __float_as_uint(mx);
    __syncthreads();
  }

  const int sr = lane >> 3;            // row within 8-row staging group
  const int sc = lane & 7;             // 16B chunk within 128B row
  const int schunk = (sc ^ sr) * 8;    // pre-swizzled global element offset

  f32x4 acc[FR][FR] = {};

  for (int k0 = 0; k0 < DIM; k0 += 64) {
    #pragma unroll
    for (int i = 0; i < FR; ++i) {
      int j = w * FR + i;              // staging slot, 8 rows each
      int r = j * 8 + sr;
      gload16(A + (size_t)(brow + r) * DIM + k0 + schunk, (char*)Alds + j * 1024);
      gload16(B + (size_t)(bcol + r) * DIM + k0 + schunk, (char*)Blds + j * 1024);
    }
    __syncthreads();
    #pragma unroll
    for (int kk = 0; kk < 2; ++kk) {
      const int koff = kk * 64 + (lane >> 4) * 16;
      short8 af[FR], bfr[FR];
      #pragma unroll
      for (int mi = 0; mi < FR; ++mi) {
        int r = wr * WSPAN + mi * 16 + (lane & 15);
        af[mi] = *(const short8*)((const char*)Alds + r * 128 + (koff ^ ((r & 7) << 4)));
      }
      #pragma unroll
      for (int ni = 0; ni < FR; ++ni) {
        int r = wc * WSPAN + ni * 16 + (lane & 15);
        bfr[ni] = *(const short8*)((const char*)Blds + r * 128 + (koff ^ ((r & 7) << 4)));
      }
      #pragma unroll
      for (int mi = 0; mi < FR; ++mi)
        #pragma unroll
        for (int ni = 0; ni < FR; ++ni)
          acc[mi][ni] = __builtin_amdgcn_mfma_f32_16x16x32_bf16(af[mi], bfr[ni], acc[mi][ni], 0, 0, 0);
    }
    __syncthreads();
  }

  // C/D layout: col = lane&15, row = (lane>>4)*4 + reg  [verified]
  if (MODE == 0) {
    #pragma unroll
    for (int mi = 0; mi < FR; ++mi)
      #pragma unroll
      for (int ni = 0; ni < FR; ++ni)
        #pragma unroll
        for (int j = 0; j < 4; ++j) {
          int row = brow + wr * WSPAN + mi * 16 + (lane >> 4) * 4 + j;
          int col = bcol + wc * WSPAN + ni * 16 + (lane & 15);
          Gfb[(size_t)row * ldc + col] = f2bf(acc[mi][ni][j]);
        }
  }
}

// ---------- 2b. S-GEMM: r10 structure + G-tile LDS prefetch (chunked over K-iters) ----------
// Gt[r][c] = G[pl[brow+r]][nl[bcol+c]] staged 16 rows per K-iteration; the vmcnt(0)
// drain at each __syncthreads already waits for staging, so gather latency is hidden.
// Epilogue reads gy from LDS — no exposed global gathers.
__global__ __launch_bounds__(256) void sgemm_kernel(
    const unsigned short* __restrict__ A, const unsigned short* __restrict__ B,
    const unsigned short* __restrict__ Gfb, unsigned short* __restrict__ Tb,
    const int* __restrict__ pl, const int* __restrict__ nl,
    const float* __restrict__ nu_loss, const unsigned* __restrict__ gbits,
    float* __restrict__ pr, float* __restrict__ pr2,
    float* __restrict__ s_part, float* __restrict__ gy_part) {
  __shared__ unsigned short Alds[128 * 64];      // 16 KB
  __shared__ unsigned short Blds[128 * 64];      // 16 KB
  __shared__ unsigned short Gt[128][136];        // 34 KB (+8 u16 pad per row)
  __shared__ int pll[128];
  __shared__ int nll[128];
  __shared__ float red[4];
  const int tid = threadIdx.x;
  const int w = tid >> 6, lane = tid & 63;
  const int brow = blockIdx.y * 128, bcol = blockIdx.x * 128;
  const int wr = w >> 1, wc = w & 1;

  if (tid < 128) pll[tid] = pl[brow + tid];
  else           nll[tid - 128] = nl[bcol + tid - 128];
  __syncthreads();

  const int sr = lane >> 3;            // row within 8-row staging group
  const int sc = lane & 7;             // 16B chunk within 128B row
  const int schunk = (sc ^ sr) * 8;    // pre-swizzled global element offset

  const int gr = tid >> 4;             // 0..15: G-prefetch row within chunk
  const int gc0 = (tid & 15) * 8;      // 8 cols per thread

  f32x4 acc[4][4] = {};

  #pragma unroll
  for (int kt = 0; kt < 8; ++kt) {
    const int k0 = kt * 64;
    {                                   // G-tile prefetch chunk: rows 16*kt..16*kt+15
      int r = kt * 16 + gr;
      const unsigned short* grow = Gfb + (size_t)pll[r] * KPAD;
      #pragma unroll
      for (int cc = 0; cc < 8; ++cc)
        Gt[r][gc0 + cc] = grow[nll[gc0 + cc]];
    }
    #pragma unroll
    for (int i = 0; i < 4; ++i) {
      int j = w * 4 + i;               // staging slot, 8 rows each
      int r = j * 8 + sr;
      gload16(A + (size_t)(brow + r) * DIM + k0 + schunk, (char*)Alds + j * 1024);
      gload16(B + (size_t)(bcol + r) * DIM + k0 + schunk, (char*)Blds + j * 1024);
    }
    __syncthreads();
    #pragma unroll
    for (int kk = 0; kk < 2; ++kk) {
      const int koff = kk * 64 + (lane >> 4) * 16;
      short8 af[4], bfr[4];
      #pragma unroll
      for (int mi = 0; mi < 4; ++mi) {
        int r = wr * 64 + mi * 16 + (lane & 15);
        af[mi] = *(const short8*)((const char*)Alds + r * 128 + (koff ^ ((r & 7) << 4)));
      }
      #pragma unroll
      for (int ni = 0; ni < 4; ++ni) {
        int r = wc * 64 + ni * 16 + (lane & 15);
        bfr[ni] = *(const short8*)((const char*)Blds + r * 128 + (koff ^ ((r & 7) << 4)));
      }
      #pragma unroll
      for (int mi = 0; mi < 4; ++mi)
        #pragma unroll
        for (int ni = 0; ni < 4; ++ni)
          acc[mi][ni] = __builtin_amdgcn_mfma_f32_16x16x32_bf16(af[mi], bfr[ni], acc[mi][ni], 0, 0, 0);
    }
    __syncthreads();
  }

  // fused DRO epilogue (C/D layout: col = lane&15, row = (lane>>4)*4 + reg)
  const float gmax = __uint_as_float(*gbits);
  const float fac = LAMBDA_ * INV_DENOM;            // ~2
  int cols[4]; int cloc[4]; float a_r[4]; float loss_r[4];
  #pragma unroll
  for (int ni = 0; ni < 4; ++ni) {
    cloc[ni]   = wc * 64 + ni * 16 + (lane & 15);
    cols[ni]   = bcol + cloc[ni];
    loss_r[ni] = nu_loss[cols[ni]];
    a_r[ni]    = (loss_r[ni] - gmax - 2.f * LAMBDA_) * INV_DENOM;
  }
  float s_acc = 0.f, gy_acc = 0.f;
  #pragma unroll
  for (int mi = 0; mi < 4; ++mi) {
    #pragma unroll
    for (int j = 0; j < 4; ++j) {
      int rloc = wr * 64 + mi * 16 + (lane >> 4) * 4 + j;
      int row = brow + rloc;
      float rowacc = 0.f, rowacc2 = 0.f;
      #pragma unroll
      for (int ni = 0; ni < 4; ++ni) {
        float s  = acc[mi][ni][j];
        float gy = bf2f(Gt[rloc][cloc[ni]]);
        float e  = fmaf(fac, s + gy, a_r[ni]);
        float t  = __expf(e);
        unsigned short tb = f2bf(t);
        Tb[(size_t)row * M_NU + cols[ni]] = tb;
        float tt = bf2f(tb);
        rowacc  += tt;
        rowacc2 += tt * loss_r[ni];
        s_acc += s; gy_acc += gy;
      }
      #pragma unroll
      for (int off = 1; off < 16; off <<= 1) {
        rowacc  += __shfl_xor(rowacc, off);
        rowacc2 += __shfl_xor(rowacc2, off);
      }
      if ((lane & 15) == 0) {
        pr [(size_t)(blockIdx.x * 2 + wc) * N_PTR + row] = rowacc;
        pr2[(size_t)(blockIdx.x * 2 + wc) * N_PTR + row] = rowacc2;
      }
    }
  }
  float stot = blk_reduce_sum(s_acc, red);
  float gtot = blk_reduce_sum(gy_acc, red);
  if (tid == 0) {
    int bid = blockIdx.y * gridDim.x + blockIdx.x;
    s_part[bid] = stot; gy_part[bid] = gtot;
  }
}

// ---------- 3. colpass (blocks 0..255) + T/D row reduce (blocks 256..271) ----------
__global__ __launch_bounds__(256) void colpass_td_kernel(
    const unsigned short* __restrict__ Tb, const float* __restrict__ pr,
    const float* __restrict__ pr2, float* __restrict__ partial,
    float* __restrict__ T_part, float* __restrict__ D_part) {
  __shared__ float sh[64];
  int b = blockIdx.x, tid = threadIdx.x;
  if (b < 256) {                       // ---- column partial: 512 m-cols x 64 n-rows
    int bx = b & 7, by = b >> 3;
    int m0 = bx * 512 + tid * 2;
    int n0 = by * 64;
    if (tid < 64) {
      float rs = 0.f;
      #pragma unroll 4
      for (int cb = 0; cb < 64; ++cb) rs += pr[(size_t)cb * N_PTR + n0 + tid];
      sh[tid] = 1.0f / (rs + EPS_);
    }
    __syncthreads();
    float a0 = 0.f, a1 = 0.f;
    #pragma unroll 4
    for (int i = 0; i < 64; ++i) {
      unsigned tv = *(const unsigned*)(Tb + (size_t)(n0 + i) * M_NU + m0);
      float wv = sh[i];
      a0 = fmaf(bf2f((unsigned short)(tv & 0xffffu)), wv, a0);
      a1 = fmaf(bf2f((unsigned short)(tv >> 16)), wv, a1);
    }
    *(float2*)(partial + (size_t)by * M_NU + m0) = make_float2(a0, a1);
  } else {                             // ---- T/D over 128 rows
    int n = (b - 256) * 128 + (tid & 127);
    float tl = 0.f, dl = 0.f;
    if (tid < 128) {
      float rs = 0.f, wl = 0.f;
      #pragma unroll 4
      for (int cb = 0; cb < 64; ++cb) {
        rs += pr [(size_t)cb * N_PTR + n];
        wl += pr2[(size_t)cb * N_PTR + n];
      }
      float wi = 1.0f / (rs + EPS_);
      tl = rs * wi; dl = wl * wi;
    }
    __syncthreads();                   // reuse sh as red scratch
    #pragma unroll
    for (int off = 32; off > 0; off >>= 1) { tl += __shfl_down(tl, off); dl += __shfl_down(dl, off); }
    if ((tid & 63) == 0) { sh[tid >> 6] = tl; sh[4 + (tid >> 6)] = dl; }
    __syncthreads();
    if (tid == 0) {
      T_part[b - 256] = sh[0] + sh[1] + sh[2] + sh[3];
      D_part[b - 256] = sh[4] + sh[5] + sh[6] + sh[7];
    }
  }
}

// ---------- 4. final: blocks 0..15 scaled probs; block 16 scalars ----------
__global__ __launch_bounds__(256) void final_kernel(const float* __restrict__ partial,
    const float* __restrict__ T_part, const float* __restrict__ D_part,
    const float* __restrict__ s_part, const float* __restrict__ gy_part,
    float* __restrict__ out) {
  __shared__ float red[4];
  int b = blockIdx.x, tid = threadIdx.x;
  float T = 0.f;
  #pragma unroll
  for (int i = 0; i < 16; ++i) T += T_part[i];
  float scale = (1.0f / (float)N_PTR) / (T / (float)N_PTR + EPS_);
  if (b < 16) {
    int m = b * 256 + tid;
    float raw = 0.f;
    #pragma unroll
    for (int c = 0; c < 32; ++c) raw += partial[(size_t)c * M_NU + m];
    out[2 + m] = raw * scale;
  } else {
    float D = 0.f;
    #pragma unroll
    for (int i = 0; i < 16; ++i) D += D_part[i];
    float ls = 0.f, lg = 0.f;
    for (int i = tid; i < 512; i += 256) { ls += s_part[i]; lg += gy_part[i]; }
    float S  = blk_reduce_sum(ls, red);
    float Gy = blk_reduce_sum(lg, red);
    if (tid == 0) {
      float dro = D * scale;
      const float invNM = 1.0f / ((float)N_PTR * (float)M_NU);
      float mcx = 1.f - S * invNM;
      float mcy = 1.f - Gy * invNM;
      out[0] = dro;
      out[1] = dro;
      out[2 + M_NU] = mcx + mcy;
      out[3 + M_NU] = mcx;
      out[4 + M_NU] = mcy;
    }
  }
}

extern "C" void kernel_launch(void* const* d_in, const int* in_sizes, int n_in,
                              void* d_out, int out_size, void* d_ws, size_t ws_size,
                              hipStream_t stream) {
  const float* ptr_feat = (const float*)d_in[0];
  const int*   ptr_lab  = (const int*)d_in[2];
  const float* nu_feat  = (const float*)d_in[3];
  const float* nu_log   = (const float*)d_in[4];
  const int*   nu_lab   = (const int*)d_in[5];
  const float* cls_w    = (const float*)d_in[6];
  float* out = (float*)d_out;

  char* base = (char*)d_ws;
  unsigned short* Tb  = (unsigned short*)base;                         // 16 MB
  unsigned short* Gfb = (unsigned short*)(base + 16u * 1024 * 1024);   // 2 MB (bf16 gram)
  unsigned short* An  = (unsigned short*)(base + 18u * 1024 * 1024);   // 2 MB
  unsigned short* Bn  = (unsigned short*)(base + 20u * 1024 * 1024);   // 4 MB
  unsigned short* Cn  = (unsigned short*)(base + 24u * 1024 * 1024);   // 1 MB
  float* fb           = (float*)(base + 25u * 1024 * 1024);
  float* nloss   = fb;                           // 4096
  unsigned* gbits= (unsigned*)(nloss + 4096);    // 1 (+63 pad)
  float* pr      = nloss + 4096 + 64;            // 64 * 2048
  float* pr2     = pr  + 64 * N_PTR;             // 64 * 2048
  float* partial = pr2 + 64 * N_PTR;             // 32 * 4096
  float* s_part  = partial + 32 * M_NU;          // 512
  float* gy_part = s_part + 512;                 // 512
  float* T_part  = gy_part + 512;                // 16
  float* D_part  = T_part + 16;                  // 16

  prep_kernel<<<dim3(1792 + M_NU), 256, 0, stream>>>(
      ptr_feat, nu_feat, cls_w, nu_log, nu_lab, An, Bn, Cn, nloss);
  mfma_gemm<64, 0><<<dim3(KPAD / 64, KPAD / 64), 256, 0, stream>>>(
      Cn, Cn, Gfb, nullptr, nullptr, nullptr, nloss, gbits,
      nullptr, nullptr, nullptr, nullptr, KPAD);
  sgemm_kernel<<<dim3(M_NU / 128, N_PTR / 128), 256, 0, stream>>>(
      An, Bn, Gfb, Tb, ptr_lab, nu_lab, nloss, gbits,
      pr, pr2, s_part, gy_part);
  colpass_td_kernel<<<dim3(272), 256, 0, stream>>>(Tb, pr, pr2, partial, T_part, D_part);
  final_kernel<<<dim3(17), 256, 0, stream>>>(partial, T_part, D_part, s_part, gy_part, out);
}

// Round 14
// 61.918 us; speedup vs baseline: 1.2393x; 1.2361x over previous
//
#include <hip/hip_runtime.h>
#include <math.h>

#define N_PTR 2048
#define M_NU  4096
#define DIM   512
#define KCLS  1000
#define KPAD  1024

static constexpr float LAMBDA_ = 0.1f;
static constexpr float EPS_ = 1e-8f;
static constexpr float INV_DENOM = 1.0f / (0.1f * 0.5f + 1e-8f);   // 1/(lambda*eps+EPS)

typedef short short8 __attribute__((ext_vector_type(8)));
typedef unsigned short u16x8 __attribute__((ext_vector_type(8)));
typedef float f32x4 __attribute__((ext_vector_type(4)));

__device__ __forceinline__ unsigned short f2bf(float x) {
  unsigned u = __float_as_uint(x);
  u += 0x7fff + ((u >> 16) & 1);     // round-to-nearest-even
  return (unsigned short)(u >> 16);
}
__device__ __forceinline__ float bf2f(unsigned short h) {
  return __uint_as_float(((unsigned)h) << 16);
}

__device__ __forceinline__ void gload16(const void* g, void* l) {
  __builtin_amdgcn_global_load_lds(
      (const __attribute__((address_space(1))) unsigned int*)g,
      (__attribute__((address_space(3))) unsigned int*)l, 16, 0, 0);
}

// ---------- block reduction helpers (blockDim.x == 256) ----------
__device__ __forceinline__ float blk_reduce_sum(float v, float* red) {
  #pragma unroll
  for (int off = 32; off > 0; off >>= 1) v += __shfl_down(v, off);
  __syncthreads();
  if ((threadIdx.x & 63) == 0) red[threadIdx.x >> 6] = v;
  __syncthreads();
  return red[0] + red[1] + red[2] + red[3];
}

__device__ __forceinline__ float blk_reduce_max(float v, float* red) {
  #pragma unroll
  for (int off = 32; off > 0; off >>= 1) v = fmaxf(v, __shfl_down(v, off));
  __syncthreads();
  if ((threadIdx.x & 63) == 0) red[threadIdx.x >> 6] = v;
  __syncthreads();
  return fmaxf(fmaxf(red[0], red[1]), fmaxf(red[2], red[3]));
}

// ---------- 1. fused prep: normalize+cast (blocks 0..1791) + CE loss (blocks 1792..5887) ----------
__global__ __launch_bounds__(256) void prep_kernel(
    const float* __restrict__ ptr_f, const float* __restrict__ nu_f,
    const float* __restrict__ cls_f, const float* __restrict__ logits,
    const int* __restrict__ labels, unsigned short* __restrict__ An,
    unsigned short* __restrict__ Bn, unsigned short* __restrict__ Cn,
    float* __restrict__ losses) {
  __shared__ float red[4];
  int b = blockIdx.x;
  if (b < 1792) {                       // ---- normalize + bf16 cast
    int gid = b * 256 + threadIdx.x;
    int row = gid >> 6, lane = gid & 63;
    const float* src; unsigned short* dst; int lrow; int in_rows;
    if (row < N_PTR)             { src = ptr_f; dst = An; lrow = row;                in_rows = N_PTR; }
    else if (row < N_PTR + M_NU) { src = nu_f;  dst = Bn; lrow = row - N_PTR;        in_rows = M_NU; }
    else                         { src = cls_f; dst = Cn; lrow = row - N_PTR - M_NU; in_rows = KCLS; }
    u16x8 ov;
    if (lrow < in_rows) {
      const float4* rp = (const float4*)(src + (size_t)lrow * DIM);
      float4 a = rp[lane * 2], bq = rp[lane * 2 + 1];
      float v[8] = {a.x, a.y, a.z, a.w, bq.x, bq.y, bq.z, bq.w};
      float s = 0.f;
      #pragma unroll
      for (int j = 0; j < 8; ++j) s = fmaf(v[j], v[j], s);
      #pragma unroll
      for (int off = 32; off > 0; off >>= 1) s += __shfl_xor(s, off);
      float inv = 1.0f / fmaxf(sqrtf(s), EPS_);
      #pragma unroll
      for (int j = 0; j < 8; ++j) ov[j] = f2bf(v[j] * inv);
    } else {
      #pragma unroll
      for (int j = 0; j < 8; ++j) ov[j] = 0;
    }
    *(u16x8*)(dst + (size_t)lrow * DIM + lane * 8) = ov;
  } else {                              // ---- CE loss (one block per nu row, float4 reads)
    int row = b - 1792;
    int tid = threadIdx.x;
    const float* x = logits + (size_t)row * KCLS;
    const float4* x4 = (const float4*)x;          // 4000B rows are 16B-aligned
    float4 v = make_float4(0.f, 0.f, 0.f, 0.f);
    float mx_loc = -INFINITY;
    if (tid < 250) {                              // 250*4 = 1000
      v = x4[tid];
      mx_loc = fmaxf(fmaxf(v.x, v.y), fmaxf(v.z, v.w));
    }
    float mx = blk_reduce_max(mx_loc, red);
    float se_loc = 0.f;
    if (tid < 250)
      se_loc = __expf(v.x - mx) + __expf(v.y - mx) + __expf(v.z - mx) + __expf(v.w - mx);
    float se = blk_reduce_sum(se_loc, red);
    if (tid == 0) losses[row] = mx + logf(se) - x[labels[row]];
  }
}

// ---------- 2. bf16 MFMA GEMM C = A @ B^T, tile BMxBM, BK=64, 4 waves 2x2 ----------
// MODE 0 (G-GEMM): 2D grid; write bf16 gram; block(0,0) first reduces gmax -> gbits.
// MODE 1 (S-GEMM): 1D grid with bijective XCD-chunked swizzle — each XCD owns a
//   contiguous bx-range (4 B-panels + full A = 2.5 MB < 4 MB per-XCD L2).
//   Fused DRO epilogue identical to r10.
template <int BM, int MODE>
__global__ __launch_bounds__(256) void mfma_gemm(
    const unsigned short* __restrict__ A, const unsigned short* __restrict__ B,
    unsigned short* __restrict__ Gfb, unsigned short* __restrict__ Tb,
    const int* __restrict__ pl, const int* __restrict__ nl,
    const float* __restrict__ nu_loss, unsigned* __restrict__ gbits,
    float* __restrict__ pr, float* __restrict__ pr2,
    float* __restrict__ s_part, float* __restrict__ gy_part, int ldc) {
  constexpr int FR = BM / 32;          // frags per wave dim (128->4, 64->2)
  constexpr int WSPAN = BM / 2;
  __shared__ unsigned short Alds[BM * 64];
  __shared__ unsigned short Blds[BM * 64];
  __shared__ float red[4];
  const int tid = threadIdx.x;
  const int w = tid >> 6, lane = tid & 63;
  int bx, by;
  if (MODE == 1) {
    int swz = (blockIdx.x & 7) * 64 + (blockIdx.x >> 3);   // bijective, 512 blocks
    bx = swz >> 4;                     // 0..31: XCD k owns bx in [4k, 4k+4)
    by = swz & 15;                     // 0..15
  } else {
    bx = blockIdx.x; by = blockIdx.y;
  }
  const int brow = by * BM, bcol = bx * BM;
  const int wr = w >> 1, wc = w & 1;

  if (MODE == 0 && blockIdx.x == 0 && blockIdx.y == 0) {
    float mloc = 0.f;
    for (int i = tid; i < M_NU; i += 256) mloc = fmaxf(mloc, nu_loss[i]);
    float mx = blk_reduce_max(mloc, red);
    if (tid == 0) *gbits = __float_as_uint(mx);
    __syncthreads();
  }

  const int sr = lane >> 3;            // row within 8-row staging group
  const int sc = lane & 7;             // 16B chunk within 128B row
  const int schunk = (sc ^ sr) * 8;    // pre-swizzled global element offset

  f32x4 acc[FR][FR] = {};

  for (int k0 = 0; k0 < DIM; k0 += 64) {
    #pragma unroll
    for (int i = 0; i < FR; ++i) {
      int j = w * FR + i;              // staging slot, 8 rows each
      int r = j * 8 + sr;
      gload16(A + (size_t)(brow + r) * DIM + k0 + schunk, (char*)Alds + j * 1024);
      gload16(B + (size_t)(bcol + r) * DIM + k0 + schunk, (char*)Blds + j * 1024);
    }
    __syncthreads();
    #pragma unroll
    for (int kk = 0; kk < 2; ++kk) {
      const int koff = kk * 64 + (lane >> 4) * 16;
      short8 af[FR], bfr[FR];
      #pragma unroll
      for (int mi = 0; mi < FR; ++mi) {
        int r = wr * WSPAN + mi * 16 + (lane & 15);
        af[mi] = *(const short8*)((const char*)Alds + r * 128 + (koff ^ ((r & 7) << 4)));
      }
      #pragma unroll
      for (int ni = 0; ni < FR; ++ni) {
        int r = wc * WSPAN + ni * 16 + (lane & 15);
        bfr[ni] = *(const short8*)((const char*)Blds + r * 128 + (koff ^ ((r & 7) << 4)));
      }
      #pragma unroll
      for (int mi = 0; mi < FR; ++mi)
        #pragma unroll
        for (int ni = 0; ni < FR; ++ni)
          acc[mi][ni] = __builtin_amdgcn_mfma_f32_16x16x32_bf16(af[mi], bfr[ni], acc[mi][ni], 0, 0, 0);
    }
    __syncthreads();
  }

  // C/D layout: col = lane&15, row = (lane>>4)*4 + reg  [verified]
  if (MODE == 0) {
    #pragma unroll
    for (int mi = 0; mi < FR; ++mi)
      #pragma unroll
      for (int ni = 0; ni < FR; ++ni)
        #pragma unroll
        for (int j = 0; j < 4; ++j) {
          int row = brow + wr * WSPAN + mi * 16 + (lane >> 4) * 4 + j;
          int col = bcol + wc * WSPAN + ni * 16 + (lane & 15);
          Gfb[(size_t)row * ldc + col] = f2bf(acc[mi][ni][j]);
        }
  } else {
    const float gmax = __uint_as_float(*gbits);
    const float fac = LAMBDA_ * INV_DENOM;            // ~2
    int cols[FR]; float a_r[FR]; float loss_r[FR]; int nl_r[FR];
    #pragma unroll
    for (int ni = 0; ni < FR; ++ni) {
      cols[ni]  = bcol + wc * WSPAN + ni * 16 + (lane & 15);
      loss_r[ni] = nu_loss[cols[ni]];
      a_r[ni]   = (loss_r[ni] - gmax - 2.f * LAMBDA_) * INV_DENOM;
      nl_r[ni]  = nl[cols[ni]];
    }
    float s_acc = 0.f, gy_acc = 0.f;
    #pragma unroll
    for (int mi = 0; mi < FR; ++mi) {
      #pragma unroll
      for (int j = 0; j < 4; ++j) {
        int row = brow + wr * WSPAN + mi * 16 + (lane >> 4) * 4 + j;
        const unsigned short* Grow = Gfb + (size_t)pl[row] * KPAD;
        float rowacc = 0.f, rowacc2 = 0.f;
        #pragma unroll
        for (int ni = 0; ni < FR; ++ni) {
          float s  = acc[mi][ni][j];
          float gy = bf2f(Grow[nl_r[ni]]);
          float e  = fmaf(fac, s + gy, a_r[ni]);
          float t  = __expf(e);
          unsigned short tb = f2bf(t);
          Tb[(size_t)row * ldc + cols[ni]] = tb;
          float tt = bf2f(tb);
          rowacc  += tt;
          rowacc2 += tt * loss_r[ni];
          s_acc += s; gy_acc += gy;
        }
        #pragma unroll
        for (int off = 1; off < 16; off <<= 1) {
          rowacc  += __shfl_xor(rowacc, off);
          rowacc2 += __shfl_xor(rowacc2, off);
        }
        if ((lane & 15) == 0) {
          pr [(size_t)(bx * 2 + wc) * N_PTR + row] = rowacc;
          pr2[(size_t)(bx * 2 + wc) * N_PTR + row] = rowacc2;
        }
      }
    }
    float stot = blk_reduce_sum(s_acc, red);
    float gtot = blk_reduce_sum(gy_acc, red);
    if (tid == 0) {
      int bid = by * 32 + bx;
      s_part[bid] = stot; gy_part[bid] = gtot;
    }
  }
}

// ---------- 3. colpass (blocks 0..255) + T/D row reduce (blocks 256..271) ----------
__global__ __launch_bounds__(256) void colpass_td_kernel(
    const unsigned short* __restrict__ Tb, const float* __restrict__ pr,
    const float* __restrict__ pr2, float* __restrict__ partial,
    float* __restrict__ T_part, float* __restrict__ D_part) {
  __shared__ float sh[64];
  int b = blockIdx.x, tid = threadIdx.x;
  if (b < 256) {                       // ---- column partial: 512 m-cols x 64 n-rows
    int bx = b & 7, by = b >> 3;
    int m0 = bx * 512 + tid * 2;
    int n0 = by * 64;
    if (tid < 64) {
      float rs = 0.f;
      #pragma unroll 4
      for (int cb = 0; cb < 64; ++cb) rs += pr[(size_t)cb * N_PTR + n0 + tid];
      sh[tid] = 1.0f / (rs + EPS_);
    }
    __syncthreads();
    float a0 = 0.f, a1 = 0.f;
    #pragma unroll 4
    for (int i = 0; i < 64; ++i) {
      unsigned tv = *(const unsigned*)(Tb + (size_t)(n0 + i) * M_NU + m0);
      float wv = sh[i];
      a0 = fmaf(bf2f((unsigned short)(tv & 0xffffu)), wv, a0);
      a1 = fmaf(bf2f((unsigned short)(tv >> 16)), wv, a1);
    }
    *(float2*)(partial + (size_t)by * M_NU + m0) = make_float2(a0, a1);
  } else {                             // ---- T/D over 128 rows
    int n = (b - 256) * 128 + (tid & 127);
    float tl = 0.f, dl = 0.f;
    if (tid < 128) {
      float rs = 0.f, wl = 0.f;
      #pragma unroll 4
      for (int cb = 0; cb < 64; ++cb) {
        rs += pr [(size_t)cb * N_PTR + n];
        wl += pr2[(size_t)cb * N_PTR + n];
      }
      float wi = 1.0f / (rs + EPS_);
      tl = rs * wi; dl = wl * wi;
    }
    __syncthreads();                   // reuse sh as red scratch
    #pragma unroll
    for (int off = 32; off > 0; off >>= 1) { tl += __shfl_down(tl, off); dl += __shfl_down(dl, off); }
    if ((tid & 63) == 0) { sh[tid >> 6] = tl; sh[4 + (tid >> 6)] = dl; }
    __syncthreads();
    if (tid == 0) {
      T_part[b - 256] = sh[0] + sh[1] + sh[2] + sh[3];
      D_part[b - 256] = sh[4] + sh[5] + sh[6] + sh[7];
    }
  }
}

// ---------- 4. final: blocks 0..15 scaled probs; block 16 scalars ----------
__global__ __launch_bounds__(256) void final_kernel(const float* __restrict__ partial,
    const float* __restrict__ T_part, const float* __restrict__ D_part,
    const float* __restrict__ s_part, const float* __restrict__ gy_part,
    float* __restrict__ out) {
  __shared__ float red[4];
  int b = blockIdx.x, tid = threadIdx.x;
  float T = 0.f;
  #pragma unroll
  for (int i = 0; i < 16; ++i) T += T_part[i];
  float scale = (1.0f / (float)N_PTR) / (T / (float)N_PTR + EPS_);
  if (b < 16) {
    int m = b * 256 + tid;
    float raw = 0.f;
    #pragma unroll
    for (int c = 0; c < 32; ++c) raw += partial[(size_t)c * M_NU + m];
    out[2 + m] = raw * scale;
  } else {
    float D = 0.f;
    #pragma unroll
    for (int i = 0; i < 16; ++i) D += D_part[i];
    float ls = 0.f, lg = 0.f;
    for (int i = tid; i < 512; i += 256) { ls += s_part[i]; lg += gy_part[i]; }
    float S  = blk_reduce_sum(ls, red);
    float Gy = blk_reduce_sum(lg, red);
    if (tid == 0) {
      float dro = D * scale;
      const float invNM = 1.0f / ((float)N_PTR * (float)M_NU);
      float mcx = 1.f - S * invNM;
      float mcy = 1.f - Gy * invNM;
      out[0] = dro;
      out[1] = dro;
      out[2 + M_NU] = mcx + mcy;
      out[3 + M_NU] = mcx;
      out[4 + M_NU] = mcy;
    }
  }
}

extern "C" void kernel_launch(void* const* d_in, const int* in_sizes, int n_in,
                              void* d_out, int out_size, void* d_ws, size_t ws_size,
                              hipStream_t stream) {
  const float* ptr_feat = (const float*)d_in[0];
  const int*   ptr_lab  = (const int*)d_in[2];
  const float* nu_feat  = (const float*)d_in[3];
  const float* nu_log   = (const float*)d_in[4];
  const int*   nu_lab   = (const int*)d_in[5];
  const float* cls_w    = (const float*)d_in[6];
  float* out = (float*)d_out;

  char* base = (char*)d_ws;
  unsigned short* Tb  = (unsigned short*)base;                         // 16 MB
  unsigned short* Gfb = (unsigned short*)(base + 16u * 1024 * 1024);   // 2 MB (bf16 gram)
  unsigned short* An  = (unsigned short*)(base + 18u * 1024 * 1024);   // 2 MB
  unsigned short* Bn  = (unsigned short*)(base + 20u * 1024 * 1024);   // 4 MB
  unsigned short* Cn  = (unsigned short*)(base + 24u * 1024 * 1024);   // 1 MB
  float* fb           = (float*)(base + 25u * 1024 * 1024);
  float* nloss   = fb;                           // 4096
  unsigned* gbits= (unsigned*)(nloss + 4096);    // 1 (+63 pad)
  float* pr      = nloss + 4096 + 64;            // 64 * 2048
  float* pr2     = pr  + 64 * N_PTR;             // 64 * 2048
  float* partial = pr2 + 64 * N_PTR;             // 32 * 4096
  float* s_part  = partial + 32 * M_NU;          // 512
  float* gy_part = s_part + 512;                 // 512
  float* T_part  = gy_part + 512;                // 16
  float* D_part  = T_part + 16;                  // 16

  prep_kernel<<<dim3(1792 + M_NU), 256, 0, stream>>>(
      ptr_feat, nu_feat, cls_w, nu_log, nu_lab, An, Bn, Cn, nloss);
  mfma_gemm<64, 0><<<dim3(KPAD / 64, KPAD / 64), 256, 0, stream>>>(
      Cn, Cn, Gfb, nullptr, nullptr, nullptr, nloss, gbits,
      nullptr, nullptr, nullptr, nullptr, KPAD);
  mfma_gemm<128, 1><<<dim3(512), 256, 0, stream>>>(
      An, Bn, Gfb, Tb, ptr_lab, nu_lab, nloss, gbits,
      pr, pr2, s_part, gy_part, M_NU);
  colpass_td_kernel<<<dim3(272), 256, 0, stream>>>(Tb, pr, pr2, partial, T_part, D_part);
  final_kernel<<<dim3(17), 256, 0, stream>>>(partial, T_part, D_part, s_part, gy_part, out);
}